// Round 6
// baseline (276.271 us; speedup 1.0000x reference)
//
#include <hip/hip_runtime.h>

// SNN_60567628808223: 2-layer LIF SNN.
//   inputs: data[16384,784] f32, W1[128,784], b1[128], W2[10,128], b2[10]
//   output: spk2 [50,16384,10] f32 (binary 0/1)
//
// CORRECTNESS INVARIANT (R2/R3): output = 8.2M binary threshold decisions;
// ulp-level reassociation flips spikes. Round-1 bits pass (absmax 0.0).
//   - cur1[m][n]: ascending-k single fmaf chain + one bias fadd. FROZEN.
//   - snn_loop: round-1 value graph FROZEN. Only data movement may change.
//
// R6 changes (gemm only; all bit-exact):
//  - B repacked (bit-copy) into per-(4k x 4n) fragments: Wt4[(kc*32+ng)*16]
//    holds W1[n=4ng+j][k=4kc+i] at [i*4+j] -> B loads are 4 CONSECUTIVE
//    dwordx4 per chunk (64 B/lane, wave-coalesced 1 KB) instead of 4
//    scattered row fragments. 401 KB -> L2-resident.
//  - 2-chunk-deep register prefetch (16 loads in flight/wave) to cover
//    L2 latency at the fixed 2-waves/SIMD occupancy (R5 was latency-bound:
//    VALUBusy 21%, Occ 20%, HBM 6% -- nothing saturated).
//  - pointer-increment addressing.

#define TSTEPS 50
#define NB 16384
#define ND 784
#define NH 128
#define NO 10

// ---------- W1 bit-copy repack: Wt4[(kc*32+ng)*16 + i*4 + j] = W1[4ng+j][4kc+i]
__global__ void w1_pack(const float* __restrict__ W1, float* __restrict__ Wt4)
{
    const int e = blockIdx.x * 256 + threadIdx.x;   // 196*32*16 = 100352
    if (e >= 196 * 32 * 16) return;
    const int r  = e & 15;
    const int g  = e >> 4;
    const int i  = r >> 2;      // k offset 0..3
    const int j  = r & 3;       // n offset 0..3
    const int kc = g >> 5;      // 0..195
    const int ng = g & 31;      // 0..31
    Wt4[e] = W1[(size_t)(ng * 4 + j) * ND + kc * 4 + i];
}

// ---------------- Phase A: exact fp32 GEMM, zero LDS, packed B -------------
// grid 512 (bm 0..255 x bn 0..1), 256 threads, 4x4 micro-tile.
__global__ __launch_bounds__(256)
void gemm_cur1(const float* __restrict__ data, const float* __restrict__ Wt4,
               const float* __restrict__ b1, float* __restrict__ cur1)
{
    const int tid  = threadIdx.x;
    const int bm   = blockIdx.x >> 1;
    const int bn   = blockIdx.x & 1;
    const int row0 = bm * 64;
    const int col0 = bn * 64;
    const int ty   = tid >> 4;
    const int tn   = tid & 15;

    const float* aP0 = data + (size_t)(row0 + ty * 4 + 0) * ND;
    const float* aP1 = data + (size_t)(row0 + ty * 4 + 1) * ND;
    const float* aP2 = data + (size_t)(row0 + ty * 4 + 2) * ND;
    const float* aP3 = data + (size_t)(row0 + ty * 4 + 3) * ND;
    // B fragment for this thread at chunk c: Wt4 + (c*32 + bn*16+tn)*16
    const float* bP  = Wt4 + (size_t)(bn * 16 + tn) * 16;   // advance 512/chunk

    float acc[4][4] = {};

    // 2-slot, 2-deep prefetch. 196 chunks = 98 x 2.
    float4 aQ[2][4], bQ[2][4];
    #pragma unroll
    for (int s = 0; s < 2; ++s) {
        const int k4 = s * 4;
        aQ[s][0] = *(const float4*)(aP0 + k4);
        aQ[s][1] = *(const float4*)(aP1 + k4);
        aQ[s][2] = *(const float4*)(aP2 + k4);
        aQ[s][3] = *(const float4*)(aP3 + k4);
        const float* bc = bP + (size_t)s * 512;
        bQ[s][0] = *(const float4*)(bc);
        bQ[s][1] = *(const float4*)(bc + 4);
        bQ[s][2] = *(const float4*)(bc + 8);
        bQ[s][3] = *(const float4*)(bc + 12);
    }

    #define DO_CHUNK(s, c)                                                    \
    {                                                                         \
        float a[4][4], b[4][4];                                               \
        _Pragma("unroll")                                                     \
        for (int r = 0; r < 4; ++r) {                                         \
            a[r][0] = aQ[s][r].x; a[r][1] = aQ[s][r].y;                       \
            a[r][2] = aQ[s][r].z; a[r][3] = aQ[s][r].w;                       \
        }                                                                     \
        _Pragma("unroll")                                                     \
        for (int i = 0; i < 4; ++i) {                                         \
            b[i][0] = bQ[s][i].x; b[i][1] = bQ[s][i].y;                       \
            b[i][2] = bQ[s][i].z; b[i][3] = bQ[s][i].w;                       \
        }                                                                     \
        if ((c) + 2 < 196) {   /* refill slot s with chunk c+2 */             \
            const int k4 = ((c) + 2) * 4;                                     \
            aQ[s][0] = *(const float4*)(aP0 + k4);                            \
            aQ[s][1] = *(const float4*)(aP1 + k4);                            \
            aQ[s][2] = *(const float4*)(aP2 + k4);                            \
            aQ[s][3] = *(const float4*)(aP3 + k4);                            \
            const float* bc = bP + (size_t)((c) + 2) * 512;                   \
            bQ[s][0] = *(const float4*)(bc);                                  \
            bQ[s][1] = *(const float4*)(bc + 4);                              \
            bQ[s][2] = *(const float4*)(bc + 8);                              \
            bQ[s][3] = *(const float4*)(bc + 12);                             \
        }                                                                     \
        /* ascending k within chunk: kk = 0..3 */                             \
        _Pragma("unroll")                                                     \
        for (int kk = 0; kk < 4; ++kk)                                        \
            _Pragma("unroll")                                                 \
            for (int i = 0; i < 4; ++i)                                       \
                _Pragma("unroll")                                             \
                for (int j = 0; j < 4; ++j)                                   \
                    acc[i][j] = fmaf(a[i][kk], b[kk][j], acc[i][j]);          \
    }

    for (int cc = 0; cc < 98; ++cc) {
        DO_CHUNK(0, 2 * cc);
        DO_CHUNK(1, 2 * cc + 1);
    }
    #undef DO_CHUNK

    float4 bv1 = *(const float4*)&b1[col0 + tn * 4];
    #pragma unroll
    for (int i = 0; i < 4; ++i) {
        float4 o;
        o.x = acc[i][0] + bv1.x;
        o.y = acc[i][1] + bv1.y;
        o.z = acc[i][2] + bv1.z;
        o.w = acc[i][3] + bv1.w;
        *(float4*)&cur1[(size_t)(row0 + ty * 4 + i) * NH + col0 + tn * 4] = o;
    }
}

// ---------------- Phase B: round-1 time loop, DPP reduce (R5, passed) ------
__device__ __forceinline__ float xmove_dpp_b1(float v) {   // lane ^ 1
    return __int_as_float(__builtin_amdgcn_update_dpp(
        0, __float_as_int(v), 0xB1, 0xF, 0xF, true));
}
__device__ __forceinline__ float xmove_dpp_b2(float v) {   // lane ^ 2
    return __int_as_float(__builtin_amdgcn_update_dpp(
        0, __float_as_int(v), 0x4E, 0xF, 0xF, true));
}
__device__ __forceinline__ float xmove_dpp_b8(float v) {   // lane ^ 8
    return __int_as_float(__builtin_amdgcn_update_dpp(
        0, __float_as_int(v), 0x128, 0xF, 0xF, true));
}
__device__ __forceinline__ float xmove_swz_b4(float v) {   // lane ^ 4
    return __int_as_float(__builtin_amdgcn_ds_swizzle(
        __float_as_int(v), 0x101F));
}

__global__ void snn_loop(const float* __restrict__ cur1,
                         const float* __restrict__ W2,
                         const float* __restrict__ b2,
                         float* __restrict__ out)
{
    const int tid = threadIdx.x;
    const int hg  = tid & 15;
    const int rl  = tid >> 4;
    const int row = blockIdx.x * 16 + rl;
    const int h0  = hg * 8;

    float w2[10][8];
    #pragma unroll
    for (int o = 0; o < 10; ++o) {
        float4 u = *(const float4*)&W2[o * NH + h0];
        float4 v = *(const float4*)&W2[o * NH + h0 + 4];
        w2[o][0] = u.x; w2[o][1] = u.y; w2[o][2] = u.z; w2[o][3] = u.w;
        w2[o][4] = v.x; w2[o][5] = v.y; w2[o][6] = v.z; w2[o][7] = v.w;
    }
    const float b2r = b2[hg < 10 ? hg : 0];

    float c[8];
    {
        float4 c0 = *(const float4*)&cur1[(size_t)row * NH + h0];
        float4 c1 = *(const float4*)&cur1[(size_t)row * NH + h0 + 4];
        c[0] = c0.x; c[1] = c0.y; c[2] = c0.z; c[3] = c0.w;
        c[4] = c1.x; c[5] = c1.y; c[6] = c1.z; c[7] = c1.w;
    }

    float mem1[8], spk1[8];
    #pragma unroll
    for (int j = 0; j < 8; ++j) { mem1[j] = 0.f; spk1[j] = 0.f; }
    float mem2 = 0.f, spk2 = 0.f;

    for (int t = 0; t < TSTEPS; ++t) {
        #pragma unroll
        for (int j = 0; j < 8; ++j) {
            float m = __fadd_rn(__fmul_rn(0.9f, mem1[j]), c[j]);
            m = __fsub_rn(m, spk1[j]);
            mem1[j] = m;
            spk1[j] = (m > 1.0f) ? 1.0f : 0.0f;
        }
        float p[10];
        #pragma unroll
        for (int o = 0; o < 10; ++o) p[o] = 0.f;
        #pragma unroll
        for (int j = 0; j < 8; ++j)
            #pragma unroll
            for (int o = 0; o < 10; ++o)
                p[o] = fmaf(spk1[j], w2[o][j], p[o]);
        #pragma unroll
        for (int o = 0; o < 10; ++o) p[o] += xmove_dpp_b1(p[o]);
        #pragma unroll
        for (int o = 0; o < 10; ++o) p[o] += xmove_dpp_b2(p[o]);
        #pragma unroll
        for (int o = 0; o < 10; ++o) p[o] += xmove_swz_b4(p[o]);
        #pragma unroll
        for (int o = 0; o < 10; ++o) p[o] += xmove_dpp_b8(p[o]);
        float tot = p[0];
        #pragma unroll
        for (int o = 1; o < 10; ++o)
            tot = (hg == o) ? p[o] : tot;
        float cur2 = __fadd_rn(tot, b2r);
        float m2 = __fsub_rn(__fadd_rn(__fmul_rn(0.9f, mem2), cur2), spk2);
        mem2 = m2;
        spk2 = (m2 > 1.0f) ? 1.0f : 0.0f;
        if (hg < 10)
            out[(size_t)t * (NB * NO) + row * NO + hg] = spk2;
    }
}

extern "C" void kernel_launch(void* const* d_in, const int* in_sizes, int n_in,
                              void* d_out, int out_size, void* d_ws, size_t ws_size,
                              hipStream_t stream) {
    const float* data = (const float*)d_in[0];
    const float* W1   = (const float*)d_in[1];
    const float* b1   = (const float*)d_in[2];
    const float* W2   = (const float*)d_in[3];
    const float* b2   = (const float*)d_in[4];
    float* out  = (float*)d_out;

    // ws: cur1 [16384*128 f32] = 8388608 B, then Wt4 [196*32*16 f32] = 401408 B
    float* cur1 = (float*)d_ws;
    float* Wt4  = (float*)((char*)d_ws + (size_t)NB * NH * 4);

    w1_pack<<<392, 256, 0, stream>>>(W1, Wt4);
    gemm_cur1<<<512, 256, 0, stream>>>(data, Wt4, b1, cur1);
    snn_loop<<<1024, 256, 0, stream>>>(cur1, W2, b2, out);
}